// Round 1
// baseline (1112.723 us; speedup 1.0000x reference)
//
#include <hip/hip_runtime.h>
#include <hip/hip_bf16.h>

// C = x[M,256] @ W[256,256], fp32 in/out, via bf16x3 split-float MFMA emulation.
// W-stationary in registers (per-wave 32-col slice, hi+lo bf16 = 128 VGPR).
// No LDS, no barriers. Persistent blocks grid-stride over 64-row tiles.

typedef short bf16x8 __attribute__((ext_vector_type(8)));   // 8 bf16 (4 VGPRs)
typedef float f32x4  __attribute__((ext_vector_type(4)));

__device__ __forceinline__ unsigned short f32_to_bf16_rne(float f) {
  unsigned u = __builtin_bit_cast(unsigned, f);
  unsigned r = u + 0x7FFFu + ((u >> 16) & 1u);   // round-to-nearest-even
  return (unsigned short)(r >> 16);
}

// x = hi + lo with hi = RTZ bf16 (top 16 bits), lo = RNE bf16 of exact remainder.
__device__ __forceinline__ void split2(float xv, short& hi, short& lo) {
  unsigned u = __builtin_bit_cast(unsigned, xv);
  hi = (short)(u >> 16);
  float hf = __builtin_bit_cast(float, u & 0xFFFF0000u);
  lo = (short)f32_to_bf16_rne(xv - hf);          // xv - hf is exact (Sterbenz)
}

__global__ __launch_bounds__(512, 2) void cp2d_kernel(
    const float* __restrict__ x, const float* __restrict__ W,
    float* __restrict__ out, int ntiles) {
  const int l   = threadIdx.x & 63;
  const int wv  = threadIdx.x >> 6;   // wave 0..7, owns cols [32*wv, 32*wv+32)
  const int l15 = l & 15;
  const int lk  = l >> 4;             // 0..3

  // ---- Load this wave's W slice into registers as bf16 hi/lo fragments ----
  // B-frag (16x16x32): lane l holds col n = base + (l&15), k = 8*(l>>4)+e, e=0..7
  bf16x8 bh[2][8], bl[2][8];
#pragma unroll
  for (int jn = 0; jn < 2; ++jn) {
    const int n = (wv << 5) + (jn << 4) + l15;
#pragma unroll
    for (int kk = 0; kk < 8; ++kk) {
      const float* p = W + ((kk << 5) + (lk << 3)) * 256 + n;
#pragma unroll
      for (int e = 0; e < 8; ++e) {
        short h, lo2;
        split2(p[e * 256], h, lo2);
        bh[jn][kk][e] = h;
        bl[jn][kk][e] = lo2;
      }
    }
  }

  // ---- Grid-stride over 64-row tiles of x ----
  for (int t = blockIdx.x; t < ntiles; t += gridDim.x) {
    const int r0 = t << 6;
    f32x4 acc[4][2];
#pragma unroll
    for (int mi = 0; mi < 4; ++mi)
#pragma unroll
      for (int jn = 0; jn < 2; ++jn)
        acc[mi][jn] = (f32x4){0.f, 0.f, 0.f, 0.f};

    // A-frag: lane l reads row r0+16*mi+(l&15), k = 32*kk + 8*(l>>4) + e
    const float* xrow = x + (r0 + l15) * 256 + (lk << 3);

#pragma unroll 2
    for (int kk = 0; kk < 8; ++kk) {
      f32x4 v0[4], v1[4];
#pragma unroll
      for (int mi = 0; mi < 4; ++mi) {
        const float* p = xrow + mi * (16 * 256) + (kk << 5);
        v0[mi] = *(const f32x4*)p;
        v1[mi] = *(const f32x4*)(p + 4);
      }
#pragma unroll
      for (int mi = 0; mi < 4; ++mi) {
        bf16x8 ah, al;
#pragma unroll
        for (int e = 0; e < 8; ++e) {
          float xv = (e < 4) ? v0[mi][e] : v1[mi][e - 4];
          short h, lo2;
          split2(xv, h, lo2);
          ah[e] = h;
          al[e] = lo2;
        }
#pragma unroll
        for (int jn = 0; jn < 2; ++jn) {
          acc[mi][jn] = __builtin_amdgcn_mfma_f32_16x16x32_bf16(ah, bh[jn][kk], acc[mi][jn], 0, 0, 0);
          acc[mi][jn] = __builtin_amdgcn_mfma_f32_16x16x32_bf16(ah, bl[jn][kk], acc[mi][jn], 0, 0, 0);
          acc[mi][jn] = __builtin_amdgcn_mfma_f32_16x16x32_bf16(al, bh[jn][kk], acc[mi][jn], 0, 0, 0);
        }
      }
    }

    // ---- Epilogue: C/D layout col = lane&15, row = 4*(lane>>4)+j (m89) ----
#pragma unroll
    for (int mi = 0; mi < 4; ++mi) {
#pragma unroll
      for (int jn = 0; jn < 2; ++jn) {
        const int col = (wv << 5) + (jn << 4) + l15;
#pragma unroll
        for (int j = 0; j < 4; ++j) {
          const int row = r0 + (mi << 4) + (lk << 2) + j;
          out[row * 256 + col] = acc[mi][jn][j];
        }
      }
    }
  }
}

extern "C" void kernel_launch(void* const* d_in, const int* in_sizes, int n_in,
                              void* d_out, int out_size, void* d_ws, size_t ws_size,
                              hipStream_t stream) {
  (void)n_in; (void)d_ws; (void)ws_size; (void)out_size;
  const float* x = (const float*)d_in[0];
  const float* W = (const float*)d_in[1];
  float* out = (float*)d_out;
  const int M = in_sizes[0] / 256;     // 401408
  const int ntiles = M / 64;           // 6272
  cp2d_kernel<<<dim3(256), dim3(512), 0, stream>>>(x, W, out, ntiles);
}